// Round 7
// baseline (89.293 us; speedup 1.0000x reference)
//
#include <hip/hip_runtime.h>
#include <stdint.h>

// Problem constants (B,C,H,W)=(4,128,64,128), R=4, D=9, out channels 81.
// out[b, di*9+dj, h, w] = sum_c src[b,c,h,w] * tgt[b,c,h+di-8,w+dj-8]
// (zero when the shifted index leaves [0,H)x[0,W); shifts are [-8,0]).
//
// v8: two-kernel split. R6 analysis: v7's MFMA math is ~1us; ~95% of its
// ~30us is per-di f32 staging + f2bf repack + barriers at 1 block/CU.
// d_ws is poisoned every iteration anyway, so conversion is hoisted into a
// one-pass kernel writing bf16 K-panel planes [c>>3][w][c&7] per (b,row)
// into d_ws; the main kernel then reads MFMA fragments DIRECTLY from
// global (one 16B load each, no LDS staging, no convert, no dbuf), one
// block per (b,h,di) -> grid 2304, LDS 4.6KB, ~24 waves/CU resident.
// Fragment mapping, band-extraction scatter, wedge-masked store reused
// verbatim from v7 (refcheck'd, absmax 0.25).
#define NB 4
#define NC 128
#define NH 64
#define NW 128
#define HW (NH * NW)      // 8192
#define ND 9
#define NOUT (ND * ND)    // 81
#define PLANE 16384       // halfwords per (b,row) bf16 K-panel plane (32 KB)
#define TGT_OFF ((size_t)NB * NH * PLANE)  // tgt planes after src planes

typedef __attribute__((ext_vector_type(8))) short short8;
typedef __attribute__((ext_vector_type(4))) float f32x4;

__device__ __forceinline__ ushort f2bf(float f) {  // RNE f32->bf16
  uint u = __float_as_uint(f);
  u += 0x7FFFu + ((u >> 16) & 1u);
  return (ushort)(u >> 16);
}

// ---- pass 1: f32 [b,c,row,w] -> bf16 K-panel planes in d_ws ----
// plane(b,row)[oct=c>>3][w][c&7]; LDS-transposed so global reads (dword,
// w-contiguous) and global writes (dwordx4, linear) are both coalesced.
__global__ __launch_bounds__(512, 2) void convert_kernel(const float* __restrict__ src,
                                                         const float* __restrict__ tgt,
                                                         ushort* __restrict__ ws) {
  __shared__ ushort pl[PLANE];
  const int t   = blockIdx.x >> 8;        // 0 = src, 1 = tgt
  const int b   = (blockIdx.x >> 6) & 3;
  const int row = blockIdx.x & 63;
  const float* in = (t ? tgt : src) + (size_t)(b * NC) * HW + row * NW;
  ushort* outp = ws + (t ? TGT_OFF : 0) + (size_t)(b * NH + row) * PLANE;

#pragma unroll
  for (int i = 0; i < 8; ++i) {
    const int cell = i * 512 + threadIdx.x;  // 4096 cells = 32 c-quads x 128 w
    const int c0 = (cell >> 7) << 2;         // 0,4,...,124
    const int w  = cell & 127;
    ushort4 e;
    e.x = f2bf(in[(size_t)(c0 + 0) * HW + w]);
    e.y = f2bf(in[(size_t)(c0 + 1) * HW + w]);
    e.z = f2bf(in[(size_t)(c0 + 2) * HW + w]);
    e.w = f2bf(in[(size_t)(c0 + 3) * HW + w]);
    // contiguous 8B write at [c0>>3][w][c0&7] (c0&7 in {0,4})
    *(ushort4*)&pl[(c0 >> 3) * 1024 + w * 8 + (c0 & 7)] = e;
  }
  __syncthreads();
#pragma unroll
  for (int i = 0; i < 4; ++i) {
    const int idx = i * 512 + threadIdx.x;   // 2048 x 16B, linear
    *(uint4*)(outp + idx * 8) = *(const uint4*)&pl[idx * 8];
  }
}

// ---- pass 2: banded Gram via MFMA, fragments straight from d_ws ----
// Block = (b,h,di); 8 waves = 8 m-tiles. Per wave: diag tile (n0=m0) and
// sub tile (n0=m0-16), K=128 as 4 chunks of 32 -> 8 MFMA.
__global__ __launch_bounds__(512, 2) void costvol_kernel(const ushort* __restrict__ ws,
                                                         float* __restrict__ out) {
  __shared__ float outlds[ND * NW];       // 4.6 KB band tile
  const int tid  = threadIdx.x;
  const int lane = tid & 63;
  const int wave = tid >> 6;              // m-tile
  const int col  = lane & 15;
  const int g    = lane >> 4;

  // XCD-pinned decode (grid 2304 = 8*288): xcd owns (b, h-half); di fastest
  // so the 9 tgt-window sharers of (b,h) are adjacent on one XCD.
  const int xcd = blockIdx.x & 7;
  const int k   = blockIdx.x >> 3;        // 0..287
  const int b   = xcd >> 1;
  const int h   = ((xcd & 1) << 5) | (k / ND);
  const int di  = k % ND;
  const int y   = h + di - 8;             // tgt row; <0 -> all-zero plane

  if (y < 0) {                            // dead plane: store zeros, done
    if (tid < ND * 32) {
      const int dj = tid >> 5;
      const int w  = (tid & 31) << 2;
      f32x4 o = {0.f, 0.f, 0.f, 0.f};
      *(f32x4*)(out + ((size_t)((b * NOUT + di * ND + dj) * NH + h)) * NW + w) = o;
    }
    return;
  }

  const ushort* ap = ws + (size_t)(b * NH + h) * PLANE;
  const ushort* tp = ws + TGT_OFF + (size_t)(b * NH + y) * PLANE;
  const int m0 = wave << 4;

  // fragment loads: lane (g,col), chunk kk -> 16B at oct=4kk+g, n=m0+col.
  short8 A[4], BD[4], BS[4];
#pragma unroll
  for (int kk = 0; kk < 4; ++kk) {
    const int off = (4 * kk + g) * 1024 + (m0 + col) * 8;
    A[kk]  = *(const short8*)&ap[off];
    BD[kk] = *(const short8*)&tp[off];
  }
  if (wave) {
#pragma unroll
    for (int kk = 0; kk < 4; ++kk)
      BS[kk] = *(const short8*)&tp[(4 * kk + g) * 1024 + (m0 - 16 + col) * 8];
  }

  f32x4 accD = {0.f, 0.f, 0.f, 0.f};
  f32x4 accS = {0.f, 0.f, 0.f, 0.f};
#pragma unroll
  for (int kk = 0; kk < 4; ++kk)
    accD = __builtin_amdgcn_mfma_f32_16x16x32_bf16(A[kk], BD[kk], accD, 0, 0, 0);
  if (wave) {
#pragma unroll
    for (int kk = 0; kk < 4; ++kk)
      accS = __builtin_amdgcn_mfma_f32_16x16x32_bf16(A[kk], BS[kk], accS, 0, 0, 0);
  }

  // band extraction (v7-verified): C/D layout col=lane&15, row=4g+reg.
  // diag: dj = col-row+8 ; sub: dj = col-row-8. Swizzled out-LDS index
  // dj*128 + ((w+4*dj)&127) spreads the dj-stride across banks.
#pragma unroll
  for (int q = 0; q < 4; ++q) {
    const int row = 4 * g + q;
    const int w   = m0 + row;
    const int djd = col - row + 8;
    if (djd >= 0 && djd <= 8)
      outlds[djd * NW + ((w + 4 * djd) & 127)] = accD[q];
    if (wave) {
      const int djs = col - row - 8;
      if (djs >= 0 && djs <= 8)
        outlds[djs * NW + ((w + 4 * djs) & 127)] = accS[q];
    }
  }
  __syncthreads();

  // store: 9 dj-rows x 128 w, coalesced float4; zero the w+dj<8 wedge
  // (stale outlds slots only ever sit under the wedge mask).
  if (tid < ND * 32) {
    const int dj = tid >> 5;
    const int w  = (tid & 31) << 2;
    f32x4 o = *(const f32x4*)&outlds[dj * NW + ((w + 4 * dj) & 127)];
#pragma unroll
    for (int i = 0; i < 4; ++i)
      if (w + i + dj < 8) o[i] = 0.f;
    *(f32x4*)(out + ((size_t)((b * NOUT + di * ND + dj) * NH + h)) * NW + w) = o;
  }
}

extern "C" void kernel_launch(void* const* d_in, const int* in_sizes, int n_in,
                              void* d_out, int out_size, void* d_ws, size_t ws_size,
                              hipStream_t stream) {
  const float* src = (const float*)d_in[0];
  const float* tgt = (const float*)d_in[1];
  float* out = (float*)d_out;
  ushort* ws = (ushort*)d_ws;
  convert_kernel<<<dim3(2 * NB * NH), dim3(512), 0, stream>>>(src, tgt, ws);
  costvol_kernel<<<dim3(NB * NH * ND), dim3(512), 0, stream>>>(ws, out);
}